// Round 1
// baseline (383.371 us; speedup 1.0000x reference)
//
#include <hip/hip_runtime.h>
#include <math.h>

#define B 32
#define C 512
#define HW 3136           // 56*56
#define HW4 784           // HW / 4 (float4 units per plane)
#define KS 3
#define PADK 1

typedef float fvec4 __attribute__((ext_vector_type(4)));

// ---------------------------------------------------------------------------
// Kernel 1: per-(b,c) mean. WAVE-per-plane: 4 planes per 256-thread block.
// No LDS, no __syncthreads. Each lane does 12-13 float4 loads, fully
// unrolled (12 loads in flight before first use -> deep MLP). Normal
// (cached) loads on purpose: this pass populates L3 with x (196 MB fits in
// the 256 MB Infinity Cache) so the scale pass re-reads mostly from L3.
// ---------------------------------------------------------------------------
__global__ __launch_bounds__(256) void mean_kernel(const float* __restrict__ x,
                                                   float* __restrict__ y) {
    const int plane = (blockIdx.x << 2) + (threadIdx.x >> 6);   // b*C + c
    const int lane  = threadIdx.x & 63;
    const fvec4* xp = (const fvec4*)(x + (size_t)plane * HW);

    float s0 = 0.f, s1 = 0.f, s2 = 0.f, s3 = 0.f;
    #pragma unroll
    for (int it = 0; it < 3; ++it) {                 // 3 * 256 = 768 float4
        const int i = lane + it * 256;
        fvec4 a = xp[i];
        fvec4 b = xp[i + 64];
        fvec4 c = xp[i + 128];
        fvec4 d = xp[i + 192];
        s0 += (a.x + a.y) + (a.z + a.w);
        s1 += (b.x + b.y) + (b.z + b.w);
        s2 += (c.x + c.y) + (c.z + c.w);
        s3 += (d.x + d.y) + (d.z + d.w);
    }
    if (lane < 16) {                                 // remainder: 768..783
        fvec4 a = xp[768 + lane];
        s0 += (a.x + a.y) + (a.z + a.w);
    }
    float s = (s0 + s1) + (s2 + s3);
    #pragma unroll
    for (int o = 32; o > 0; o >>= 1) s += __shfl_down(s, o, 64);
    if (lane == 0) y[plane] = s * (1.0f / (float)HW);
}

// ---------------------------------------------------------------------------
// Kernel 2: attention scalars. One thread per (b,c). 16384 threads total =
// 64 blocks. y is 64 KB -> L2/L3 resident; this kernel is ~3 us and removes
// the serial thread-0 prologue + __syncthreads from the streaming pass.
// ---------------------------------------------------------------------------
__global__ __launch_bounds__(256) void attn_kernel(
        const float* __restrict__ y,
        const float* __restrict__ w_offset,
        const float* __restrict__ w_deform,
        const float* __restrict__ b_deform,
        float* __restrict__ attn) {
    const int id = blockIdx.x * 256 + threadIdx.x;   // plane = b*C + p
    const int b  = id >> 9;                          // / C
    const int p  = id & (C - 1);                     // % C
    const float* yb = y + b * C;

    const float ym1 = (p >= 1)    ? yb[p - 1] : 0.f; // zero-padded conv input
    const float y0  = yb[p];
    const float yp1 = (p < C - 1) ? yb[p + 1] : 0.f;

    float acc = b_deform[0];
    #pragma unroll
    for (int k = 0; k < KS; ++k) {
        const float off = w_offset[k * KS + 0] * ym1
                        + w_offset[k * KS + 1] * y0
                        + w_offset[k * KS + 2] * yp1;
        const float pos  = (float)(p + k - PADK) + off;
        const float p0f  = floorf(pos);
        const float frac = pos - p0f;
        const int   i0   = (int)p0f;
        const int   i1   = i0 + 1;
        const float v0 = (i0 >= 0 && i0 < C) ? yb[i0] : 0.f;
        const float v1 = (i1 >= 0 && i1 < C) ? yb[i1] : 0.f;
        acc += w_deform[k] * (v0 * (1.f - frac) + v1 * frac);
    }
    attn[id] = 1.f / (1.f + expf(-acc));
}

// ---------------------------------------------------------------------------
// Kernel 3: out = attn * x. WAVE-per-plane, fully unrolled (12 float4
// loads in flight per lane), no sync, no divergent prologue. NORMAL stores:
// the fill kernels prove the plain store path sustains 6.5 TB/s; this round
// A/B-tests the hypothesis that __builtin_nontemporal_store was the 4x
// throttle in the previous version.
// ---------------------------------------------------------------------------
__global__ __launch_bounds__(256) void scale_kernel(
        const float* __restrict__ x,
        const float* __restrict__ attn,
        float* __restrict__ out) {
    const int plane = (blockIdx.x << 2) + (threadIdx.x >> 6);
    const int lane  = threadIdx.x & 63;
    const float a   = attn[plane];                   // one 4B load per wave, L2-hit
    const fvec4* xp = (const fvec4*)(x + (size_t)plane * HW);
    fvec4*       op = (fvec4*)(out + (size_t)plane * HW);

    #pragma unroll
    for (int it = 0; it < 12; ++it) {                // 12 * 64 = 768 float4
        const int i = lane + it * 64;
        fvec4 v = xp[i];
        v *= a;
        op[i] = v;
    }
    if (lane < 16) {                                 // remainder: 768..783
        const int i = 768 + lane;
        fvec4 v = xp[i];
        v *= a;
        op[i] = v;
    }
}

extern "C" void kernel_launch(void* const* d_in, const int* in_sizes, int n_in,
                              void* d_out, int out_size, void* d_ws, size_t ws_size,
                              hipStream_t stream) {
    const float* x        = (const float*)d_in[0];   // (32,512,56,56)
    const float* w_offset = (const float*)d_in[1];   // (3,1,3)
    const float* w_deform = (const float*)d_in[2];   // (3,)
    const float* b_deform = (const float*)d_in[3];   // scalar
    float* out  = (float*)d_out;

    float* y    = (float*)d_ws;                      // B*C floats
    float* attn = (float*)d_ws + B * C;              // B*C floats

    mean_kernel <<<B * C / 4,   256, 0, stream>>>(x, y);
    attn_kernel <<<B * C / 256, 256, 0, stream>>>(y, w_offset, w_deform,
                                                  b_deform, attn);
    scale_kernel<<<B * C / 4,   256, 0, stream>>>(x, attn, out);
}

// Round 2
// 373.655 us; speedup vs baseline: 1.0260x; 1.0260x over previous
//
#include <hip/hip_runtime.h>
#include <math.h>

#define B 32
#define C 512
#define HW 3136           // 56*56
#define HW4 784           // HW / 4 (float4 units per plane)
#define KS 3
#define PADK 1

typedef float fvec4 __attribute__((ext_vector_type(4)));  // native vector: ok for nontemporal builtins

// ---------------------------------------------------------------------------
// Kernel 1: per-(b,c) mean. WAVE-per-plane: 4 planes per 256-thread block.
// No LDS, no __syncthreads. Each lane does 12-13 float4 loads, fully
// unrolled. NORMAL (cached) loads on purpose: this pass populates L3 with x
// (205 MB fits in the 256 MB Infinity Cache) so the scale pass re-reads x
// from L3 instead of HBM.
// ---------------------------------------------------------------------------
__global__ __launch_bounds__(256) void mean_kernel(const float* __restrict__ x,
                                                   float* __restrict__ y) {
    const int plane = (blockIdx.x << 2) + (threadIdx.x >> 6);   // b*C + c
    const int lane  = threadIdx.x & 63;
    const fvec4* xp = (const fvec4*)(x + (size_t)plane * HW);

    float s0 = 0.f, s1 = 0.f, s2 = 0.f, s3 = 0.f;
    #pragma unroll
    for (int it = 0; it < 3; ++it) {                 // 3 * 256 = 768 float4
        const int i = lane + it * 256;
        fvec4 a = xp[i];
        fvec4 b = xp[i + 64];
        fvec4 c = xp[i + 128];
        fvec4 d = xp[i + 192];
        s0 += (a.x + a.y) + (a.z + a.w);
        s1 += (b.x + b.y) + (b.z + b.w);
        s2 += (c.x + c.y) + (c.z + c.w);
        s3 += (d.x + d.y) + (d.z + d.w);
    }
    if (lane < 16) {                                 // remainder: 768..783
        fvec4 a = xp[768 + lane];
        s0 += (a.x + a.y) + (a.z + a.w);
    }
    float s = (s0 + s1) + (s2 + s3);
    #pragma unroll
    for (int o = 32; o > 0; o >>= 1) s += __shfl_down(s, o, 64);
    if (lane == 0) y[plane] = s * (1.0f / (float)HW);
}

// ---------------------------------------------------------------------------
// Kernel 2: attention scalars. One thread per (b,c). 64 blocks total.
// y is 64 KB -> L2/L3 resident; ~3 us. Keeps the serial scalar math and its
// dependent L2-latency loads out of the streaming pass entirely.
// ---------------------------------------------------------------------------
__global__ __launch_bounds__(256) void attn_kernel(
        const float* __restrict__ y,
        const float* __restrict__ w_offset,
        const float* __restrict__ w_deform,
        const float* __restrict__ b_deform,
        float* __restrict__ attn) {
    const int id = blockIdx.x * 256 + threadIdx.x;   // plane = b*C + p
    const int b  = id >> 9;                          // / C
    const int p  = id & (C - 1);                     // % C
    const float* yb = y + b * C;

    const float ym1 = (p >= 1)    ? yb[p - 1] : 0.f; // zero-padded conv input
    const float y0  = yb[p];
    const float yp1 = (p < C - 1) ? yb[p + 1] : 0.f;

    float acc = b_deform[0];
    #pragma unroll
    for (int k = 0; k < KS; ++k) {
        const float off = w_offset[k * KS + 0] * ym1
                        + w_offset[k * KS + 1] * y0
                        + w_offset[k * KS + 2] * yp1;
        const float pos  = (float)(p + k - PADK) + off;
        const float p0f  = floorf(pos);
        const float frac = pos - p0f;
        const int   i0   = (int)p0f;
        const int   i1   = i0 + 1;
        const float v0 = (i0 >= 0 && i0 < C) ? yb[i0] : 0.f;
        const float v1 = (i1 >= 0 && i1 < C) ? yb[i1] : 0.f;
        acc += w_deform[k] * (v0 * (1.f - frac) + v1 * frac);
    }
    attn[id] = 1.f / (1.f + expf(-acc));
}

// ---------------------------------------------------------------------------
// Kernel 3: out = attn * x. WAVE-per-plane, fully unrolled, no sync.
// NON-TEMPORAL stores restored (single-variable A/B vs Round 1): out is
// write-once dead data — NT keeps it from write-allocating into L3 and
// evicting x, so the x reads here stay L3 hits. Round-0(NT)=370.3 vs
// Round-1(no-NT)=383.4 is the evidence.
// ---------------------------------------------------------------------------
__global__ __launch_bounds__(256) void scale_kernel(
        const float* __restrict__ x,
        const float* __restrict__ attn,
        float* __restrict__ out) {
    const int plane = (blockIdx.x << 2) + (threadIdx.x >> 6);
    const int lane  = threadIdx.x & 63;
    const float a   = attn[plane];                   // one 4B load per wave, L2-hit
    const fvec4* xp = (const fvec4*)(x + (size_t)plane * HW);
    fvec4*       op = (fvec4*)(out + (size_t)plane * HW);

    #pragma unroll
    for (int it = 0; it < 12; ++it) {                // 12 * 64 = 768 float4
        const int i = lane + it * 64;
        fvec4 v = xp[i];
        v *= a;
        __builtin_nontemporal_store(v, &op[i]);      // nt: don't evict x from L3
    }
    if (lane < 16) {                                 // remainder: 768..783
        const int i = 768 + lane;
        fvec4 v = xp[i];
        v *= a;
        __builtin_nontemporal_store(v, &op[i]);
    }
}

extern "C" void kernel_launch(void* const* d_in, const int* in_sizes, int n_in,
                              void* d_out, int out_size, void* d_ws, size_t ws_size,
                              hipStream_t stream) {
    const float* x        = (const float*)d_in[0];   // (32,512,56,56)
    const float* w_offset = (const float*)d_in[1];   // (3,1,3)
    const float* w_deform = (const float*)d_in[2];   // (3,)
    const float* b_deform = (const float*)d_in[3];   // scalar
    float* out  = (float*)d_out;

    float* y    = (float*)d_ws;                      // B*C floats
    float* attn = (float*)d_ws + B * C;              // B*C floats

    mean_kernel <<<B * C / 4,   256, 0, stream>>>(x, y);
    attn_kernel <<<B * C / 256, 256, 0, stream>>>(y, w_offset, w_deform,
                                                  b_deform, attn);
    scale_kernel<<<B * C / 4,   256, 0, stream>>>(x, attn, out);
}

// Round 4
// 371.841 us; speedup vs baseline: 1.0310x; 1.0049x over previous
//
#include <hip/hip_runtime.h>
#include <math.h>

#define B 32
#define C 512
#define HW 3136           // 56*56
#define HW4 784           // HW / 4 (float4 units per plane)
#define KS 3
#define PADK 1

typedef float fvec4 __attribute__((ext_vector_type(4)));  // native vector: ok for nontemporal builtins

// ---------------------------------------------------------------------------
// Kernel 1: per-(b,c) mean. WAVE-per-plane: 4 planes per 256-thread block.
// No LDS, no __syncthreads. Fully unrolled, 12 loads in flight per lane.
// NORMAL (cached) loads on purpose: populates L3 with x (205 MB fits in the
// 256 MB Infinity Cache) so the scale pass re-reads x from L3, not HBM.
// ---------------------------------------------------------------------------
__global__ __launch_bounds__(256) void mean_kernel(const float* __restrict__ x,
                                                   float* __restrict__ y) {
    const int plane = (blockIdx.x << 2) + (threadIdx.x >> 6);   // b*C + c
    const int lane  = threadIdx.x & 63;
    const fvec4* xp = (const fvec4*)(x + (size_t)plane * HW);

    float s0 = 0.f, s1 = 0.f, s2 = 0.f, s3 = 0.f;
    #pragma unroll
    for (int it = 0; it < 3; ++it) {                 // 3 * 256 = 768 float4
        const int i = lane + it * 256;
        fvec4 a = xp[i];
        fvec4 b = xp[i + 64];
        fvec4 c = xp[i + 128];
        fvec4 d = xp[i + 192];
        s0 += (a.x + a.y) + (a.z + a.w);
        s1 += (b.x + b.y) + (b.z + b.w);
        s2 += (c.x + c.y) + (c.z + c.w);
        s3 += (d.x + d.y) + (d.z + d.w);
    }
    if (lane < 16) {                                 // remainder: 768..783
        fvec4 a = xp[768 + lane];
        s0 += (a.x + a.y) + (a.z + a.w);
    }
    float s = (s0 + s1) + (s2 + s3);
    #pragma unroll
    for (int o = 32; o > 0; o >>= 1) s += __shfl_down(s, o, 64);
    if (lane == 0) y[plane] = s * (1.0f / (float)HW);
}

// ---------------------------------------------------------------------------
// Kernel 2 (fused attn + scale): wave-per-plane, NO LDS / NO barrier.
// Every lane of a wave redundantly computes its plane's attention scalar —
// p is wave-uniform, so all y loads are broadcast (1 transaction) and all
// branches are wave-uniform. The first 4 float4 of x are prefetched into
// registers BEFORE the attn math so its ~9 dependent L2-latency loads
// overlap the x stream instead of serializing ahead of it.
// NT stores: out is write-once dead data; keeps x L3-resident (A/B: R1
// no-NT = 383.4 vs R2 NT = 373.7).
// ---------------------------------------------------------------------------
__global__ __launch_bounds__(256) void scale_attn_kernel(
        const float* __restrict__ x,
        const float* __restrict__ y,
        const float* __restrict__ w_offset,
        const float* __restrict__ w_deform,
        const float* __restrict__ b_deform,
        float* __restrict__ out) {
    const int plane = (blockIdx.x << 2) + (threadIdx.x >> 6);   // b*C + c
    const int lane  = threadIdx.x & 63;
    const int b = plane >> 9;                        // / C
    const int p = plane & (C - 1);                   // % C
    const float* yb = y + b * C;

    const fvec4* xp = (const fvec4*)(x + (size_t)plane * HW);
    fvec4*       op = (fvec4*)(out + (size_t)plane * HW);

    // ---- prefetch iteration 0 of the x stream (independent of attn) ------
    fvec4 v0 = xp[lane];
    fvec4 v1 = xp[lane + 64];
    fvec4 v2 = xp[lane + 128];
    fvec4 v3 = xp[lane + 192];

    // ---- attn scalar (redundant on all 64 lanes; wave-uniform) -----------
    const float ym1 = (p >= 1)    ? yb[p - 1] : 0.f; // zero-padded conv input
    const float y0  = yb[p];
    const float yp1 = (p < C - 1) ? yb[p + 1] : 0.f;

    float acc = b_deform[0];
    #pragma unroll
    for (int k = 0; k < KS; ++k) {
        const float off = w_offset[k * KS + 0] * ym1
                        + w_offset[k * KS + 1] * y0
                        + w_offset[k * KS + 2] * yp1;
        const float pos  = (float)(p + k - PADK) + off;
        const float p0f  = floorf(pos);
        const float frac = pos - p0f;
        const int   i0   = (int)p0f;
        const int   i1   = i0 + 1;
        const float s0 = (i0 >= 0 && i0 < C) ? yb[i0] : 0.f;
        const float s1 = (i1 >= 0 && i1 < C) ? yb[i1] : 0.f;
        acc += w_deform[k] * (s0 * (1.f - frac) + s1 * frac);
    }
    const float a = 1.f / (1.f + expf(-acc));

    // ---- drain the prefetched batch --------------------------------------
    v0 *= a; __builtin_nontemporal_store(v0, &op[lane]);
    v1 *= a; __builtin_nontemporal_store(v1, &op[lane + 64]);
    v2 *= a; __builtin_nontemporal_store(v2, &op[lane + 128]);
    v3 *= a; __builtin_nontemporal_store(v3, &op[lane + 192]);

    // ---- rest of the plane ------------------------------------------------
    #pragma unroll
    for (int it = 4; it < 12; ++it) {                // 8 * 64 more float4
        const int i = lane + it * 64;
        fvec4 v = xp[i];
        v *= a;
        __builtin_nontemporal_store(v, &op[i]);
    }
    if (lane < 16) {                                 // remainder: 768..783
        const int i = 768 + lane;
        fvec4 v = xp[i];
        v *= a;
        __builtin_nontemporal_store(v, &op[i]);
    }
}

extern "C" void kernel_launch(void* const* d_in, const int* in_sizes, int n_in,
                              void* d_out, int out_size, void* d_ws, size_t ws_size,
                              hipStream_t stream) {
    const float* x        = (const float*)d_in[0];   // (32,512,56,56)
    const float* w_offset = (const float*)d_in[1];   // (3,1,3)
    const float* w_deform = (const float*)d_in[2];   // (3,)
    const float* b_deform = (const float*)d_in[3];   // scalar
    float* out  = (float*)d_out;
    float* y    = (float*)d_ws;                      // B*C floats

    mean_kernel      <<<B * C / 4, 256, 0, stream>>>(x, y);
    scale_attn_kernel<<<B * C / 4, 256, 0, stream>>>(x, y, w_offset, w_deform,
                                                     b_deform, out);
}

// Round 6
// 370.184 us; speedup vs baseline: 1.0356x; 1.0045x over previous
//
#include <hip/hip_runtime.h>
#include <math.h>

#define B 32
#define C 512
#define HW 3136           // 56*56
#define KS 3
#define PADK 1

typedef float fvec4 __attribute__((ext_vector_type(4)));  // native vector: ok for nontemporal builtins

// ---------------------------------------------------------------------------
// Kernel 1: per-(b,c) mean. WAVE-per-plane: 4 planes per 256-thread block.
// No LDS, no __syncthreads. Fully unrolled, 12 loads in flight per lane.
// NORMAL (cached) loads on purpose: populates the 256 MB Infinity Cache with
// x (196 MiB fits) so the scale pass re-reads x from L3, not HBM.
// ---------------------------------------------------------------------------
__global__ __launch_bounds__(256) void mean_kernel(const float* __restrict__ x,
                                                   float* __restrict__ y) {
    const int plane = (blockIdx.x << 2) + (threadIdx.x >> 6);   // b*C + c
    const int lane  = threadIdx.x & 63;
    const fvec4* xp = (const fvec4*)(x + (size_t)plane * HW);

    float s0 = 0.f, s1 = 0.f, s2 = 0.f, s3 = 0.f;
    #pragma unroll
    for (int it = 0; it < 3; ++it) {                 // 3 * 256 = 768 float4
        const int i = lane + it * 256;
        fvec4 a = xp[i];
        fvec4 b = xp[i + 64];
        fvec4 c = xp[i + 128];
        fvec4 d = xp[i + 192];
        s0 += (a.x + a.y) + (a.z + a.w);
        s1 += (b.x + b.y) + (b.z + b.w);
        s2 += (c.x + c.y) + (c.z + c.w);
        s3 += (d.x + d.y) + (d.z + d.w);
    }
    if (lane < 16) {                                 // remainder: 768..783
        fvec4 a = xp[768 + lane];
        s0 += (a.x + a.y) + (a.z + a.w);
    }
    float s = (s0 + s1) + (s2 + s3);
    #pragma unroll
    for (int o = 32; o > 0; o >>= 1) s += __shfl_down(s, o, 64);
    if (lane == 0) y[plane] = s * (1.0f / (float)HW);
}

// ---------------------------------------------------------------------------
// Kernel 2 (fused attn + scale): wave-per-plane, NO LDS / NO barrier.
// Every lane redundantly computes its plane's attention scalar — p is
// wave-uniform, so all y loads are broadcast and all branches are
// wave-uniform. The first 4 float4 of x are prefetched into registers BEFORE
// the attn math so its ~9 dependent L2-latency loads overlap the x stream.
// NT stores: out is write-once dead data; keeps x L3-resident
// (A/B evidence: R1 no-NT = 383.4 vs R2 NT = 373.7).
// NOTE: hipLaunchCooperativeKernel is unusable in this harness — R3 silently
// no-ops at capture, R5 hung the container at replay. Do not reintroduce.
// ---------------------------------------------------------------------------
__global__ __launch_bounds__(256) void scale_attn_kernel(
        const float* __restrict__ x,
        const float* __restrict__ y,
        const float* __restrict__ w_offset,
        const float* __restrict__ w_deform,
        const float* __restrict__ b_deform,
        float* __restrict__ out) {
    const int plane = (blockIdx.x << 2) + (threadIdx.x >> 6);   // b*C + c
    const int lane  = threadIdx.x & 63;
    const int b = plane >> 9;                        // / C
    const int p = plane & (C - 1);                   // % C
    const float* yb = y + b * C;

    const fvec4* xp = (const fvec4*)(x + (size_t)plane * HW);
    fvec4*       op = (fvec4*)(out + (size_t)plane * HW);

    // ---- prefetch iteration 0 of the x stream (independent of attn) ------
    fvec4 v0 = xp[lane];
    fvec4 v1 = xp[lane + 64];
    fvec4 v2 = xp[lane + 128];
    fvec4 v3 = xp[lane + 192];

    // ---- attn scalar (redundant on all 64 lanes; wave-uniform) -----------
    const float ym1 = (p >= 1)    ? yb[p - 1] : 0.f; // zero-padded conv input
    const float y0  = yb[p];
    const float yp1 = (p < C - 1) ? yb[p + 1] : 0.f;

    float acc = b_deform[0];
    #pragma unroll
    for (int k = 0; k < KS; ++k) {
        const float off = w_offset[k * KS + 0] * ym1
                        + w_offset[k * KS + 1] * y0
                        + w_offset[k * KS + 2] * yp1;
        const float pos  = (float)(p + k - PADK) + off;
        const float p0f  = floorf(pos);
        const float frac = pos - p0f;
        const int   i0   = (int)p0f;
        const int   i1   = i0 + 1;
        const float s0 = (i0 >= 0 && i0 < C) ? yb[i0] : 0.f;
        const float s1 = (i1 >= 0 && i1 < C) ? yb[i1] : 0.f;
        acc += w_deform[k] * (s0 * (1.f - frac) + s1 * frac);
    }
    const float a = 1.f / (1.f + expf(-acc));

    // ---- drain the prefetched batch --------------------------------------
    v0 *= a; __builtin_nontemporal_store(v0, &op[lane]);
    v1 *= a; __builtin_nontemporal_store(v1, &op[lane + 64]);
    v2 *= a; __builtin_nontemporal_store(v2, &op[lane + 128]);
    v3 *= a; __builtin_nontemporal_store(v3, &op[lane + 192]);

    // ---- rest of the plane ------------------------------------------------
    #pragma unroll
    for (int it = 4; it < 12; ++it) {                // 8 * 64 more float4
        const int i = lane + it * 64;
        fvec4 v = xp[i];
        v *= a;
        __builtin_nontemporal_store(v, &op[i]);
    }
    if (lane < 16) {                                 // remainder: 768..783
        const int i = 768 + lane;
        fvec4 v = xp[i];
        v *= a;
        __builtin_nontemporal_store(v, &op[i]);
    }
}

extern "C" void kernel_launch(void* const* d_in, const int* in_sizes, int n_in,
                              void* d_out, int out_size, void* d_ws, size_t ws_size,
                              hipStream_t stream) {
    const float* x        = (const float*)d_in[0];   // (32,512,56,56)
    const float* w_offset = (const float*)d_in[1];   // (3,1,3)
    const float* w_deform = (const float*)d_in[2];   // (3,)
    const float* b_deform = (const float*)d_in[3];   // scalar
    float* out  = (float*)d_out;
    float* y    = (float*)d_ws;                      // B*C floats

    mean_kernel      <<<B * C / 4, 256, 0, stream>>>(x, y);
    scale_attn_kernel<<<B * C / 4, 256, 0, stream>>>(x, y, w_offset, w_deform,
                                                     b_deform, out);
}